// Round 10
// baseline (246.550 us; speedup 1.0000x reference)
//
#include <hip/hip_runtime.h>
#include <hip/hip_bf16.h>
#include <math.h>

// SAM2 MultiScale Block — round 17: mlp 16-token blocks (16x16x32 MFMA).
//  - mlp: 2048 blocks x 256 thr, 16 tokens each. LDS 72.7K -> 36.4K ->
//    4 blocks/CU (2x block parallelism for HBM-burst overlap). Balanced
//    waves: GEMM1 14 tiles/wave (2x7 indep chains), GEMM2 {4,4,3,3}.
//  - cast_w: m1F/m2F repacked to 16x16 frag order (qkvF formula).
// attn identical to R16.
// DIM=112(K pad 128), DIM_OUT=224, HEADS=4, HD=56, WS=8, QS=2, MLP=896
//
// ws layout (bytes):
//   hs2   @ 29,360,128 : 32768x224 f32   = 29,360,128
//   wF    @ 73,400,320 : frag-packed bf16 weights (elems):
//     qkvF 704x128 @ +0       rpF 224x128 @ +90112   apF 224x224 @ +118784
//     m1F  896x224 @ +168960  m2F 224x896 @ +369664  (end 570368)
// 16x16 frag order (ALL weights now): (n,k) -> tile=(n/16)*KT+(k/32);
//   flat=(tile*64+lane)*8+j, lane=((k%32)/8)*16+(n%16), j=k%8.
//   KT: qkvF=4, rpF=4, apF=7, m1F=7, m2F=28.

#define SCALE_A 0.13363062095621219f  // 56^-0.5

typedef __attribute__((ext_vector_type(8))) short short8;
typedef __attribute__((ext_vector_type(4))) short short4v;
typedef __attribute__((ext_vector_type(4))) float f32x4;
typedef __attribute__((ext_vector_type(16))) float f32x16;

__device__ inline short f2bf(float x) {
  __hip_bfloat16 h = __float2bfloat16(x);  // RNE, lowers to v_cvt_pk_bf16_f32
  union { __hip_bfloat16 h; short s; } u; u.h = h;
  return u.s;
}
// sigmoid-form tanh-GELU: x * sigmoid(1.59576912*(x + 0.044715 x^3)).
__device__ inline float gelu_fast(float x) {
  float x2 = x * x;
  float p = fmaf(x2, 0.044715f, 1.0f);
  float t = -1.5957691216057308f * x * p;
  return x / (1.0f + __expf(t));
}

// ------------------------------------------- weight cast to frag order
__global__ void cast_w_kernel(const float* __restrict__ qkv_w,
                              const float* __restrict__ rp_w,
                              const float* __restrict__ ap_w,
                              const float* __restrict__ m1_w,
                              const float* __restrict__ m2_w,
                              short* __restrict__ wF) {
  int tid = blockIdx.x * blockDim.x + threadIdx.x;
  int stride = gridDim.x * blockDim.x;
  // qkvF: permuted cols cp = h*176 + cl; cl: [q 0..55|k 56..111|v 112..167|pad]
  for (int e = tid; e < 90112; e += stride) {
    int j = e & 7, lr = (e >> 3) & 15, lqq = (e >> 7) & 3, tile = e >> 9;
    int kt = tile & 3, nt = tile >> 2;
    int cp = nt * 16 + lr;
    int h = cp / 176, cl = cp % 176;
    int k = kt * 32 + lqq * 8 + j;
    float val = 0.f;
    if (k < 112 && cl < 168) {
      int bcol = (cl < 56) ? (h * 56 + cl)
               : (cl < 112) ? (224 + h * 56 + (cl - 56))
                            : (448 + h * 56 + (cl - 112));
      val = qkv_w[k * 672 + bcol];
    }
    wF[e] = f2bf(val);
  }
  for (int e = tid; e < 28672; e += stride) {  // rpF: N=224, KT=4 (16x16)
    int j = e & 7, lr = (e >> 3) & 15, lqq = (e >> 7) & 3, tile = e >> 9;
    int kt = tile & 3, nt = tile >> 2;
    int n = nt * 16 + lr, k = kt * 32 + lqq * 8 + j;
    wF[90112 + e] = (k < 112) ? f2bf(rp_w[k * 224 + n]) : (short)0;
  }
  for (int e = tid; e < 50176; e += stride) {  // apF: N=224, KT=7 (16x16)
    int j = e & 7, lr = (e >> 3) & 15, lqq = (e >> 7) & 3, tile = e >> 9;
    int kt = tile % 7, nt = tile / 7;
    int n = nt * 16 + lr, k = kt * 32 + lqq * 8 + j;
    wF[118784 + e] = f2bf(ap_w[k * 224 + n]);
  }
  for (int e = tid; e < 200704; e += stride) {  // m1F: N=896, K=224, KT=7 (16x16)
    int j = e & 7, lr = (e >> 3) & 15, lqq = (e >> 7) & 3, tile = e >> 9;
    int kt = tile % 7, nt = tile / 7;
    int n = nt * 16 + lr, k = kt * 32 + lqq * 8 + j;
    wF[168960 + e] = f2bf(m1_w[k * 896 + n]);
  }
  for (int e = tid; e < 200704; e += stride) {  // m2F: N=224, K=896, KT=28 (16x16)
    int j = e & 7, lr = (e >> 3) & 15, lqq = (e >> 7) & 3, tile = e >> 9;
    int kt = tile % 28, nt = tile / 28;
    int n = nt * 16 + lr, k = kt * 32 + lqq * 8 + j;
    wF[369664 + e] = f2bf(m2_w[k * 224 + n]);
  }
}

// --- fused LN1 + windowed attention + attn_proj + res_proj/maxpool (R16)
__global__ __launch_bounds__(256, 2) void attn_kernel(
    const float* __restrict__ x, const float* __restrict__ ln1_g,
    const float* __restrict__ ln1_b, const short* __restrict__ qkvF,
    const float* __restrict__ qkv_b, const short* __restrict__ apF,
    const float* __restrict__ apb, const short* __restrict__ rpF,
    const float* __restrict__ rpb, float* __restrict__ hs2) {
  __shared__ alignas(16) short u_s[4 * 9792];   // 78,336 B
  int win = blockIdx.x;                         // 2048
  int nw = win & 15, nh = (win >> 4) & 15, b = win >> 8;
  int tid = threadIdx.x;
  int wave = tid >> 6, lane = tid & 63, lrow = lane & 15, lq = lane >> 4;
  short* w_s  = u_s;                    // [64*136] LN'd tokens (hoist only)
  short* k_s  = u_s + wave * 9792;      // private
  short* vT_s = k_s + 4608;
  short* qp_s = k_s + 8640;             // q -> P -> o(head) region

  // ---- staging + LN1: 4 lanes/token, lane owns 28 contiguous channels
  {
    int part = tid & 3, m = tid >> 2;   // token m, quarter part
    int p = m >> 2, r = m & 3;
    int tr = (p >> 2) * 2 + (r >> 1), tc = (p & 3) * 2 + (r & 1);
    size_t token = ((size_t)(b * 128 + nh * 8 + tr)) * 128 + (nw * 8 + tc);
    const float* xp = x + token * 112 + part * 28;
    f32x4 v[7];
    #pragma unroll
    for (int i = 0; i < 7; ++i) v[i] = *(const f32x4*)(xp + i * 4);
    float s = 0.f;
    #pragma unroll
    for (int i = 0; i < 7; ++i) s += v[i][0] + v[i][1] + v[i][2] + v[i][3];
    s += __shfl_xor(s, 1, 4);
    s += __shfl_xor(s, 2, 4);
    float mean = s * (1.f / 112.f);
    float s2 = 0.f;
    #pragma unroll
    for (int i = 0; i < 7; ++i)
      #pragma unroll
      for (int q = 0; q < 4; ++q) { float d = v[i][q] - mean; s2 = fmaf(d, d, s2); }
    s2 += __shfl_xor(s2, 1, 4);
    s2 += __shfl_xor(s2, 2, 4);
    float rs = rsqrtf(s2 * (1.f / 112.f) + 1e-6f);
    const float* gp = ln1_g + part * 28;
    const float* bp = ln1_b + part * 28;
    #pragma unroll
    for (int i = 0; i < 7; ++i) {
      f32x4 gg = *(const f32x4*)(gp + i * 4);
      f32x4 bb = *(const f32x4*)(bp + i * 4);
      short4v o;
      #pragma unroll
      for (int q = 0; q < 4; ++q)
        o[q] = f2bf((v[i][q] - mean) * rs * gg[q] + bb[q]);
      *(short4v*)&w_s[m * 136 + part * 28 + i * 4] = o;
    }
  }
  // zero pad cols 112..135 (192 threads x short8)
  if (tid < 192) {
    short8 z = {0, 0, 0, 0, 0, 0, 0, 0};
    *(short8*)&w_s[(tid / 3) * 136 + 112 + (tid % 3) * 8] = z;
  }
  __syncthreads();  // staging + LN done

  // hoist A-frags for all 4 M-tiles: 64 VGPR (live through respool!)
  short8 Aw[4][4];
  #pragma unroll
  for (int mt = 0; mt < 4; ++mt)
    #pragma unroll
    for (int kt = 0; kt < 4; ++kt)
      Aw[mt][kt] = *(const short8*)&w_s[(mt * 16 + lrow) * 136 + kt * 32 + lq * 8];
  __syncthreads();  // hoists done; per-wave regions may be written

  // zero pads (per-wave, one short8 store per lane)
  {
    short8 z = {0, 0, 0, 0, 0, 0, 0, 0};
    *(short8*)&k_s[lane * 72 + 56] = z;          // k pad cols 56..63, 64 rows
    if (lane < 16) *(short8*)&qp_s[lane * 72 + 56] = z;  // q pad
  }

  int h = wave;  // head ownership

  // ---- qkv: 11 N-tiles for this head, all 4 M-tiles
  #pragma unroll 2
  for (int t = 0; t < 11; ++t) {
    int cl = t * 16 + lrow;
    f32x4 ac[4] = {{0.f,0.f,0.f,0.f},{0.f,0.f,0.f,0.f},
                   {0.f,0.f,0.f,0.f},{0.f,0.f,0.f,0.f}};
    short8 bw[4];
    #pragma unroll
    for (int kt = 0; kt < 4; ++kt)
      bw[kt] = *(const short8*)(qkvF + (((h * 11 + t) * 4 + kt) * 64 + lane) * 8);
    #pragma unroll
    for (int kt = 0; kt < 4; ++kt)
      #pragma unroll
      for (int mt = 0; mt < 4; ++mt)
        ac[mt] = __builtin_amdgcn_mfma_f32_16x16x32_bf16(Aw[mt][kt], bw[kt], ac[mt], 0, 0, 0);
    if (cl < 56) {
      float bias = qkv_b[h * 56 + cl];
      #pragma unroll
      for (int mt = 0; mt < 4; ++mt) {
        float mx = fmaxf(fmaxf(ac[mt][0], ac[mt][1]),
                         fmaxf(ac[mt][2], ac[mt][3])) + bias;
        qp_s[(mt * 4 + lq) * 72 + cl] = f2bf(mx * SCALE_A);
      }
    } else if (cl < 112) {
      float bias = qkv_b[224 + h * 56 + (cl - 56)];
      #pragma unroll
      for (int mt = 0; mt < 4; ++mt)
        #pragma unroll
        for (int r = 0; r < 4; ++r)
          k_s[(mt * 16 + lq * 4 + r) * 72 + (cl - 56)] = f2bf(ac[mt][r] + bias);
    } else if (cl < 168) {
      float bias = qkv_b[448 + h * 56 + (cl - 112)];
      #pragma unroll
      for (int mt = 0; mt < 4; ++mt) {
        short4v pk = {f2bf(ac[mt][0] + bias), f2bf(ac[mt][1] + bias),
                      f2bf(ac[mt][2] + bias), f2bf(ac[mt][3] + bias)};
        *(short4v*)&vT_s[(cl - 112) * 72 + mt * 16 + lq * 4] = pk;
      }
    }
  }
  // no barrier: same-wave LDS write->read (waitcnt handles it)

  // ---- scores: 16 queries x 64 keys
  short8 aq[2];
  #pragma unroll
  for (int kt = 0; kt < 2; ++kt)
    aq[kt] = *(const short8*)&qp_s[lrow * 72 + kt * 32 + lq * 8];
  f32x4 sc[4];
  #pragma unroll
  for (int t = 0; t < 4; ++t) {
    sc[t][0] = sc[t][1] = sc[t][2] = sc[t][3] = 0.f;
    #pragma unroll
    for (int kt = 0; kt < 2; ++kt) {
      short8 bk = *(const short8*)&k_s[(t * 16 + lrow) * 72 + kt * 32 + lq * 8];
      sc[t] = __builtin_amdgcn_mfma_f32_16x16x32_bf16(aq[kt], bk, sc[t], 0, 0, 0);
    }
  }
  // ---- softmax rows lq*4+r: reduce over t (local) and lrow (16-lane shfl)
  float mr[4], sr[4];
  #pragma unroll
  for (int r = 0; r < 4; ++r)
    mr[r] = fmaxf(fmaxf(sc[0][r], sc[1][r]), fmaxf(sc[2][r], sc[3][r]));
  #pragma unroll
  for (int off = 8; off; off >>= 1)
    #pragma unroll
    for (int r = 0; r < 4; ++r) mr[r] = fmaxf(mr[r], __shfl_xor(mr[r], off, 16));
  #pragma unroll
  for (int r = 0; r < 4; ++r) {
    #pragma unroll
    for (int t = 0; t < 4; ++t) sc[t][r] = __expf(sc[t][r] - mr[r]);
    sr[r] = sc[0][r] + sc[1][r] + sc[2][r] + sc[3][r];
  }
  #pragma unroll
  for (int off = 8; off; off >>= 1)
    #pragma unroll
    for (int r = 0; r < 4; ++r) sr[r] += __shfl_xor(sr[r], off, 16);
  #pragma unroll
  for (int r = 0; r < 4; ++r) sr[r] = 1.f / sr[r];
  // normalized P -> qp_s (q is dead; same-wave write->read, no barrier)
  #pragma unroll
  for (int t = 0; t < 4; ++t)
    #pragma unroll
    for (int r = 0; r < 4; ++r)
      qp_s[(lq * 4 + r) * 72 + t * 16 + lrow] = f2bf(sc[t][r] * sr[r]);

  // ---- PV: all 56 cols; tiles {0,16,32,40}, 4th overlaps (store lrow>=8).
  short8 ap[2];
  #pragma unroll
  for (int kt = 0; kt < 2; ++kt)
    ap[kt] = *(const short8*)&qp_s[lrow * 72 + kt * 32 + lq * 8];
  #pragma unroll
  for (int ct = 0; ct < 4; ++ct) {
    int c0 = (ct < 3) ? ct * 16 : 40;
    int col = c0 + lrow;
    f32x4 ov = {0.f, 0.f, 0.f, 0.f};
    #pragma unroll
    for (int kt = 0; kt < 2; ++kt) {
      short8 bv = *(const short8*)&vT_s[col * 72 + kt * 32 + lq * 8];
      ov = __builtin_amdgcn_mfma_f32_16x16x32_bf16(ap[kt], bv, ov, 0, 0, 0);
    }
    if (ct < 3 || lrow >= 8) {
      #pragma unroll
      for (int r = 0; r < 4; ++r)
        qp_s[(lq * 4 + r) * 72 + col] = f2bf(ov[r]);  // o (head h), same-wave
    }
  }

  // ---- respool compute PRE-barrier (Aw regs + rpF from L2; no LDS deps).
  int nt0 = (wave < 2) ? wave * 4 : 8 + (wave - 2) * 3;
  int ncnt2 = (wave < 2) ? 4 : 3;
  float resv[4][4];
  #pragma unroll
  for (int i = 0; i < 4; ++i) {
    if (i < ncnt2) {  // wave-uniform guard
      int nt = nt0 + i;
      f32x4 racc[4] = {{0.f,0.f,0.f,0.f},{0.f,0.f,0.f,0.f},
                       {0.f,0.f,0.f,0.f},{0.f,0.f,0.f,0.f}};
      short8 rw[4];
      #pragma unroll
      for (int kt = 0; kt < 4; ++kt)
        rw[kt] = *(const short8*)(rpF + (((nt * 4) + kt) * 64 + lane) * 8);
      #pragma unroll
      for (int kt = 0; kt < 4; ++kt)
        #pragma unroll
        for (int mt = 0; mt < 4; ++mt)
          racc[mt] = __builtin_amdgcn_mfma_f32_16x16x32_bf16(Aw[mt][kt], rw[kt], racc[mt], 0, 0, 0);
      float bi = rpb[nt * 16 + lrow];
      #pragma unroll
      for (int mt = 0; mt < 4; ++mt)
        resv[i][mt] = fmaxf(fmaxf(racc[mt][0], racc[mt][1]),
                            fmaxf(racc[mt][2], racc[mt][3])) + bi;
    }
  }
  __syncthreads();  // all heads' o ready; all k/vT regions now DEAD

  // res -> res_s f32[16][228] over dead w_s/k/vT region (same-wave reads later)
  float* res_s = (float*)u_s;
  #pragma unroll
  for (int i = 0; i < 4; ++i) {
    if (i < ncnt2) {
      int nt = nt0 + i;
      #pragma unroll
      for (int mt = 0; mt < 4; ++mt)
        res_s[(mt * 4 + lq) * 228 + nt * 16 + lrow] = resv[i][mt];
    }
  }

  // ---- fused attn_proj: A = o rows 0..15 (K=224 spread over head regions)
  short8 Ao[7];
  #pragma unroll
  for (int kt = 0; kt < 7; ++kt) {
    int c = kt * 32 + lq * 8;               // o channel 0..216
    int h2 = (c >= 168) ? 3 : (c >= 112) ? 2 : (c >= 56) ? 1 : 0;
    Ao[kt] = *(const short8*)&u_s[h2 * 9792 + 8640 + lrow * 72 + (c - h2 * 56)];
  }
  for (int i = 0; i < ncnt2; ++i) {
    int nt = nt0 + i;
    f32x4 acc = {0.f, 0.f, 0.f, 0.f};
    #pragma unroll
    for (int kt = 0; kt < 7; ++kt) {
      short8 bw = *(const short8*)(apF + ((nt * 7 + kt) * 64 + lane) * 8);
      acc = __builtin_amdgcn_mfma_f32_16x16x32_bf16(Ao[kt], bw, acc, 0, 0, 0);
    }
    int col2 = nt * 16 + lrow;
    float bi = apb[col2];
    #pragma unroll
    for (int r = 0; r < 4; ++r) {
      float res = res_s[(lq * 4 + r) * 228 + col2];
      size_t token = ((size_t)(b * 64 + nh * 4 + lq)) * 64 + nw * 4 + r;
      hs2[token * 224 + col2] = res + acc[r] + bi;
    }
  }
}

// ------------- fused LN2 + mlp1 + GELU + mlp2 + residual, R17:
// 16 tokens/block, 256 threads, 16x16x32 MFMA, 4 blocks/CU.
__device__ __forceinline__ void mlp1_g7(
    int nt0, const short* ln_s, const short* __restrict__ m1F,
    const float* __restrict__ b1, short* hid_s, int lrow, int lq, int lane) {
  f32x4 acc[7];
  #pragma unroll
  for (int i = 0; i < 7; ++i) { acc[i][0] = acc[i][1] = acc[i][2] = acc[i][3] = 0.f; }
  #pragma unroll
  for (int kt = 0; kt < 7; ++kt) {
    short8 a = *(const short8*)&ln_s[lrow * 232 + kt * 32 + lq * 8];
    #pragma unroll
    for (int i = 0; i < 7; ++i) {
      short8 bw = *(const short8*)(m1F + ((size_t)((nt0 + i) * 7 + kt) * 64 + lane) * 8);
      acc[i] = __builtin_amdgcn_mfma_f32_16x16x32_bf16(a, bw, acc[i], 0, 0, 0);
    }
  }
  #pragma unroll
  for (int i = 0; i < 7; ++i) {
    int col = (nt0 + i) * 16 + lrow;
    float bi = b1[col];
    #pragma unroll
    for (int r = 0; r < 4; ++r)
      hid_s[(lq * 4 + r) * 904 + col] = f2bf(gelu_fast(acc[i][r] + bi));
  }
}

__global__ __launch_bounds__(256, 4) void mlp_kernel(
    const float* __restrict__ hs2, const float* __restrict__ g2,
    const float* __restrict__ b2, const short* __restrict__ m1F,
    const float* __restrict__ b1, const short* __restrict__ m2F,
    const float* __restrict__ b2b, float* __restrict__ out) {
  __shared__ alignas(16) short ln_s[16 * 232];   //  7,424 B
  __shared__ alignas(16) short hid_s[16 * 904];  // 28,928 B => 36,352 B
  int blk = blockIdx.x;  // 2048 x 16 tokens
  int tid = threadIdx.x;
  size_t base = (size_t)blk * 16 * 224;
  {
    // LN2: row = tid>>4 (0..15), lane l owns 14 contiguous channels
    int row = tid >> 4, l = tid & 15;
    const float* rp = hs2 + base + (size_t)row * 224 + l * 14;
    float v[14];
    float s = 0.f;
    #pragma unroll
    for (int c = 0; c < 7; ++c) {
      float2 t = *(const float2*)(rp + 2 * c);
      v[2 * c] = t.x; v[2 * c + 1] = t.y;
      s += t.x + t.y;
    }
    #pragma unroll
    for (int off = 8; off; off >>= 1) s += __shfl_xor(s, off, 16);
    float mean = s * (1.f / 224.f);
    float s2 = 0.f;
    #pragma unroll
    for (int c = 0; c < 14; ++c) { float d = v[c] - mean; s2 = fmaf(d, d, s2); }
    #pragma unroll
    for (int off = 8; off; off >>= 1) s2 += __shfl_xor(s2, off, 16);
    float rs = rsqrtf(s2 * (1.f / 224.f) + 1e-6f);
    const float* gp = g2 + l * 14;
    const float* bp = b2 + l * 14;
    #pragma unroll
    for (int c = 0; c < 7; ++c) {
      float2 gg = *(const float2*)(gp + 2 * c);
      float2 bb = *(const float2*)(bp + 2 * c);
      unsigned lo = (unsigned short)f2bf((v[2 * c] - mean) * rs * gg.x + bb.x);
      unsigned hi = (unsigned short)f2bf((v[2 * c + 1] - mean) * rs * gg.y + bb.y);
      *(unsigned*)&ln_s[row * 232 + l * 14 + 2 * c] = lo | (hi << 16);
    }
  }
  __syncthreads();
  int wave = tid >> 6, lane = tid & 63;
  int lrow = lane & 15, lq = lane >> 4;
  // GEMM1: 56 N-tiles, 14/wave as 2 groups of 7 independent chains
  mlp1_g7(wave * 14, ln_s, m1F, b1, hid_s, lrow, lq, lane);
  mlp1_g7(wave * 14 + 7, ln_s, m1F, b1, hid_s, lrow, lq, lane);
  __syncthreads();
  // GEMM2: 14 N-tiles, waves {4,4,3,3}
  int nt0 = (wave < 2) ? wave * 4 : 8 + (wave - 2) * 3;
  int cnt = (wave < 2) ? 4 : 3;
  float res[4][4];
  #pragma unroll
  for (int i = 0; i < 4; ++i) {
    if (i < cnt) {  // wave-uniform guard (static indexing)
      int col = (nt0 + i) * 16 + lrow;
      #pragma unroll
      for (int r = 0; r < 4; ++r)
        res[i][r] = hs2[base + (size_t)(lq * 4 + r) * 224 + col];
    }
  }
  f32x4 ac[4];
  #pragma unroll
  for (int i = 0; i < 4; ++i) { ac[i][0] = ac[i][1] = ac[i][2] = ac[i][3] = 0.f; }
  #pragma unroll 4
  for (int kt = 0; kt < 28; ++kt) {
    short8 a = *(const short8*)&hid_s[lrow * 904 + kt * 32 + lq * 8];
    #pragma unroll
    for (int i = 0; i < 4; ++i) {
      if (i < cnt) {
        short8 bw = *(const short8*)(m2F + ((size_t)((nt0 + i) * 28 + kt) * 64 + lane) * 8);
        ac[i] = __builtin_amdgcn_mfma_f32_16x16x32_bf16(a, bw, ac[i], 0, 0, 0);
      }
    }
  }
  #pragma unroll
  for (int i = 0; i < 4; ++i) {
    if (i < cnt) {
      int col = (nt0 + i) * 16 + lrow;
      float bi = b2b[col];
      #pragma unroll
      for (int r = 0; r < 4; ++r) {
        size_t idx = base + (size_t)(lq * 4 + r) * 224 + col;
        out[idx] = res[i][r] + ac[i][r] + bi;
      }
    }
  }
}

extern "C" void kernel_launch(void* const* d_in, const int* in_sizes, int n_in,
                              void* d_out, int out_size, void* d_ws, size_t ws_size,
                              hipStream_t stream) {
  const float* x    = (const float*)d_in[0];
  const float* ln1g = (const float*)d_in[1];
  const float* ln1b = (const float*)d_in[2];
  const float* qkvw = (const float*)d_in[3];
  const float* qkvb = (const float*)d_in[4];
  const float* apw  = (const float*)d_in[5];
  const float* apb  = (const float*)d_in[6];
  const float* rpw  = (const float*)d_in[7];
  const float* rpb  = (const float*)d_in[8];
  const float* ln2g = (const float*)d_in[9];
  const float* ln2b = (const float*)d_in[10];
  const float* w1   = (const float*)d_in[11];
  const float* b1   = (const float*)d_in[12];
  const float* w2   = (const float*)d_in[13];
  const float* b2   = (const float*)d_in[14];
  float* out = (float*)d_out;

  float* hs2 = (float*)((char*)d_ws + 29360128);
  short* wF  = (short*)((char*)d_ws + 73400320);

  cast_w_kernel<<<1024, 256, 0, stream>>>(qkvw, rpw, apw, w1, w2, wF);
  attn_kernel<<<2048, 256, 0, stream>>>(x, ln1g, ln1b, wF, qkvb, wF + 118784,
                                        apb, wF + 90112, rpb, hs2);
  mlp_kernel<<<2048, 256, 0, stream>>>(hs2, ln2g, ln2b, wF + 168960, b1,
                                       wF + 369664, b2, out);
}

// Round 11
// 214.417 us; speedup vs baseline: 1.1499x; 1.1499x over previous
//
#include <hip/hip_runtime.h>
#include <hip/hip_bf16.h>
#include <math.h>

// SAM2 MultiScale Block — round 18: REVERT mlp/cast to R16 (R17's 16-token
// mlp doubled L2 weight traffic 0.8->1.6GB, added 1.26M bank-conflict cyc,
// 2x MFMA instrs -> 57->88us). mlp 32-token/32x32 is the reuse/ILP optimum.
// attn: qkv t-loop unroll 2 -> 4 (more L2 loads in flight; latency-bound at
// 2 waves/SIMD). Everything else identical to R16.
// DIM=112(K pad 128), DIM_OUT=224, HEADS=4, HD=56, WS=8, QS=2, MLP=896
//
// ws layout (bytes):
//   hs2   @ 29,360,128 : 32768x224 f32   = 29,360,128
//   wF    @ 73,400,320 : frag-packed bf16 weights (elems):
//     qkvF 704x128 @ +0       rpF 224x128 @ +90112   apF 224x224 @ +118784
//     m1F  896x224 @ +168960  m2F 224x896 @ +369664  (end 570368)
// 16x16 frag order (qkvF/rpF/apF): (n,k) -> tile=(n/16)*KT+(k/32);
//   flat=(tile*64+lane)*8+j, lane=((k%32)/8)*16+(n%16), j=k%8.
// 32x32 frag order (m1F/m2F): (n,k) -> tile=(n/32)*KT16+(k/16);
//   flat=(tile*64+lane)*8+j, lane=((k%16)/8)*32+(n%32), j=k%8.

#define SCALE_A 0.13363062095621219f  // 56^-0.5

typedef __attribute__((ext_vector_type(8))) short short8;
typedef __attribute__((ext_vector_type(4))) short short4v;
typedef __attribute__((ext_vector_type(4))) float f32x4;
typedef __attribute__((ext_vector_type(16))) float f32x16;

__device__ inline short f2bf(float x) {
  __hip_bfloat16 h = __float2bfloat16(x);  // RNE, lowers to v_cvt_pk_bf16_f32
  union { __hip_bfloat16 h; short s; } u; u.h = h;
  return u.s;
}
// sigmoid-form tanh-GELU: x * sigmoid(1.59576912*(x + 0.044715 x^3)).
__device__ inline float gelu_fast(float x) {
  float x2 = x * x;
  float p = fmaf(x2, 0.044715f, 1.0f);
  float t = -1.5957691216057308f * x * p;
  return x / (1.0f + __expf(t));
}

// ------------------------------------------- weight cast to frag order
__global__ void cast_w_kernel(const float* __restrict__ qkv_w,
                              const float* __restrict__ rp_w,
                              const float* __restrict__ ap_w,
                              const float* __restrict__ m1_w,
                              const float* __restrict__ m2_w,
                              short* __restrict__ wF) {
  int tid = blockIdx.x * blockDim.x + threadIdx.x;
  int stride = gridDim.x * blockDim.x;
  // qkvF: permuted cols cp = h*176 + cl; cl: [q 0..55|k 56..111|v 112..167|pad]
  for (int e = tid; e < 90112; e += stride) {
    int j = e & 7, lr = (e >> 3) & 15, lqq = (e >> 7) & 3, tile = e >> 9;
    int kt = tile & 3, nt = tile >> 2;
    int cp = nt * 16 + lr;
    int h = cp / 176, cl = cp % 176;
    int k = kt * 32 + lqq * 8 + j;
    float val = 0.f;
    if (k < 112 && cl < 168) {
      int bcol = (cl < 56) ? (h * 56 + cl)
               : (cl < 112) ? (224 + h * 56 + (cl - 56))
                            : (448 + h * 56 + (cl - 112));
      val = qkv_w[k * 672 + bcol];
    }
    wF[e] = f2bf(val);
  }
  for (int e = tid; e < 28672; e += stride) {  // rpF: N=224, KT=4 (16x16)
    int j = e & 7, lr = (e >> 3) & 15, lqq = (e >> 7) & 3, tile = e >> 9;
    int kt = tile & 3, nt = tile >> 2;
    int n = nt * 16 + lr, k = kt * 32 + lqq * 8 + j;
    wF[90112 + e] = (k < 112) ? f2bf(rp_w[k * 224 + n]) : (short)0;
  }
  for (int e = tid; e < 50176; e += stride) {  // apF: N=224, KT=7 (16x16)
    int j = e & 7, lr = (e >> 3) & 15, lqq = (e >> 7) & 3, tile = e >> 9;
    int kt = tile % 7, nt = tile / 7;
    int n = nt * 16 + lr, k = kt * 32 + lqq * 8 + j;
    wF[118784 + e] = f2bf(ap_w[k * 224 + n]);
  }
  for (int e = tid; e < 200704; e += stride) {  // m1F: N=896/32, K=224/16 (32x32)
    int j = e & 7, lane = (e >> 3) & 63, unit = e >> 9;
    int kt = unit % 14, nt = unit / 14;
    int n = nt * 32 + (lane & 31), k = kt * 16 + (lane >> 5) * 8 + j;
    wF[168960 + e] = f2bf(m1_w[k * 896 + n]);
  }
  for (int e = tid; e < 200704; e += stride) {  // m2F: N=224/32, K=896/16 (32x32)
    int j = e & 7, lane = (e >> 3) & 63, unit = e >> 9;
    int kt = unit % 56, nt = unit / 56;
    int n = nt * 32 + (lane & 31), k = kt * 16 + (lane >> 5) * 8 + j;
    wF[369664 + e] = f2bf(m2_w[k * 224 + n]);
  }
}

// --- fused LN1 + windowed attention + attn_proj + res_proj/maxpool, R18
__global__ __launch_bounds__(256, 2) void attn_kernel(
    const float* __restrict__ x, const float* __restrict__ ln1_g,
    const float* __restrict__ ln1_b, const short* __restrict__ qkvF,
    const float* __restrict__ qkv_b, const short* __restrict__ apF,
    const float* __restrict__ apb, const short* __restrict__ rpF,
    const float* __restrict__ rpb, float* __restrict__ hs2) {
  __shared__ alignas(16) short u_s[4 * 9792];   // 78,336 B
  int win = blockIdx.x;                         // 2048
  int nw = win & 15, nh = (win >> 4) & 15, b = win >> 8;
  int tid = threadIdx.x;
  int wave = tid >> 6, lane = tid & 63, lrow = lane & 15, lq = lane >> 4;
  short* w_s  = u_s;                    // [64*136] LN'd tokens (hoist only)
  short* k_s  = u_s + wave * 9792;      // private
  short* vT_s = k_s + 4608;
  short* qp_s = k_s + 8640;             // q -> P -> o(head) region

  // ---- staging + LN1: 4 lanes/token, lane owns 28 contiguous channels
  {
    int part = tid & 3, m = tid >> 2;   // token m, quarter part
    int p = m >> 2, r = m & 3;
    int tr = (p >> 2) * 2 + (r >> 1), tc = (p & 3) * 2 + (r & 1);
    size_t token = ((size_t)(b * 128 + nh * 8 + tr)) * 128 + (nw * 8 + tc);
    const float* xp = x + token * 112 + part * 28;
    f32x4 v[7];
    #pragma unroll
    for (int i = 0; i < 7; ++i) v[i] = *(const f32x4*)(xp + i * 4);
    float s = 0.f;
    #pragma unroll
    for (int i = 0; i < 7; ++i) s += v[i][0] + v[i][1] + v[i][2] + v[i][3];
    s += __shfl_xor(s, 1, 4);
    s += __shfl_xor(s, 2, 4);
    float mean = s * (1.f / 112.f);
    float s2 = 0.f;
    #pragma unroll
    for (int i = 0; i < 7; ++i)
      #pragma unroll
      for (int q = 0; q < 4; ++q) { float d = v[i][q] - mean; s2 = fmaf(d, d, s2); }
    s2 += __shfl_xor(s2, 1, 4);
    s2 += __shfl_xor(s2, 2, 4);
    float rs = rsqrtf(s2 * (1.f / 112.f) + 1e-6f);
    const float* gp = ln1_g + part * 28;
    const float* bp = ln1_b + part * 28;
    #pragma unroll
    for (int i = 0; i < 7; ++i) {
      f32x4 gg = *(const f32x4*)(gp + i * 4);
      f32x4 bb = *(const f32x4*)(bp + i * 4);
      short4v o;
      #pragma unroll
      for (int q = 0; q < 4; ++q)
        o[q] = f2bf((v[i][q] - mean) * rs * gg[q] + bb[q]);
      *(short4v*)&w_s[m * 136 + part * 28 + i * 4] = o;
    }
  }
  // zero pad cols 112..135 (192 threads x short8)
  if (tid < 192) {
    short8 z = {0, 0, 0, 0, 0, 0, 0, 0};
    *(short8*)&w_s[(tid / 3) * 136 + 112 + (tid % 3) * 8] = z;
  }
  __syncthreads();  // staging + LN done

  // hoist A-frags for all 4 M-tiles: 64 VGPR (live through respool!)
  short8 Aw[4][4];
  #pragma unroll
  for (int mt = 0; mt < 4; ++mt)
    #pragma unroll
    for (int kt = 0; kt < 4; ++kt)
      Aw[mt][kt] = *(const short8*)&w_s[(mt * 16 + lrow) * 136 + kt * 32 + lq * 8];
  __syncthreads();  // hoists done; per-wave regions may be written

  // zero pads (per-wave, one short8 store per lane)
  {
    short8 z = {0, 0, 0, 0, 0, 0, 0, 0};
    *(short8*)&k_s[lane * 72 + 56] = z;          // k pad cols 56..63, 64 rows
    if (lane < 16) *(short8*)&qp_s[lane * 72 + 56] = z;  // q pad
  }

  int h = wave;  // head ownership

  // ---- qkv: 11 N-tiles for this head, all 4 M-tiles (unroll 4: ~8 L2 loads
  // in flight across iterations; latency-bound at 2 waves/SIMD)
  #pragma unroll 4
  for (int t = 0; t < 11; ++t) {
    int cl = t * 16 + lrow;
    f32x4 ac[4] = {{0.f,0.f,0.f,0.f},{0.f,0.f,0.f,0.f},
                   {0.f,0.f,0.f,0.f},{0.f,0.f,0.f,0.f}};
    short8 bw[4];
    #pragma unroll
    for (int kt = 0; kt < 4; ++kt)
      bw[kt] = *(const short8*)(qkvF + (((h * 11 + t) * 4 + kt) * 64 + lane) * 8);
    #pragma unroll
    for (int kt = 0; kt < 4; ++kt)
      #pragma unroll
      for (int mt = 0; mt < 4; ++mt)
        ac[mt] = __builtin_amdgcn_mfma_f32_16x16x32_bf16(Aw[mt][kt], bw[kt], ac[mt], 0, 0, 0);
    if (cl < 56) {
      float bias = qkv_b[h * 56 + cl];
      #pragma unroll
      for (int mt = 0; mt < 4; ++mt) {
        float mx = fmaxf(fmaxf(ac[mt][0], ac[mt][1]),
                         fmaxf(ac[mt][2], ac[mt][3])) + bias;
        qp_s[(mt * 4 + lq) * 72 + cl] = f2bf(mx * SCALE_A);
      }
    } else if (cl < 112) {
      float bias = qkv_b[224 + h * 56 + (cl - 56)];
      #pragma unroll
      for (int mt = 0; mt < 4; ++mt)
        #pragma unroll
        for (int r = 0; r < 4; ++r)
          k_s[(mt * 16 + lq * 4 + r) * 72 + (cl - 56)] = f2bf(ac[mt][r] + bias);
    } else if (cl < 168) {
      float bias = qkv_b[448 + h * 56 + (cl - 112)];
      #pragma unroll
      for (int mt = 0; mt < 4; ++mt) {
        short4v pk = {f2bf(ac[mt][0] + bias), f2bf(ac[mt][1] + bias),
                      f2bf(ac[mt][2] + bias), f2bf(ac[mt][3] + bias)};
        *(short4v*)&vT_s[(cl - 112) * 72 + mt * 16 + lq * 4] = pk;
      }
    }
  }
  // no barrier: same-wave LDS write->read (waitcnt handles it)

  // ---- scores: 16 queries x 64 keys
  short8 aq[2];
  #pragma unroll
  for (int kt = 0; kt < 2; ++kt)
    aq[kt] = *(const short8*)&qp_s[lrow * 72 + kt * 32 + lq * 8];
  f32x4 sc[4];
  #pragma unroll
  for (int t = 0; t < 4; ++t) {
    sc[t][0] = sc[t][1] = sc[t][2] = sc[t][3] = 0.f;
    #pragma unroll
    for (int kt = 0; kt < 2; ++kt) {
      short8 bk = *(const short8*)&k_s[(t * 16 + lrow) * 72 + kt * 32 + lq * 8];
      sc[t] = __builtin_amdgcn_mfma_f32_16x16x32_bf16(aq[kt], bk, sc[t], 0, 0, 0);
    }
  }
  // ---- softmax rows lq*4+r: reduce over t (local) and lrow (16-lane shfl)
  float mr[4], sr[4];
  #pragma unroll
  for (int r = 0; r < 4; ++r)
    mr[r] = fmaxf(fmaxf(sc[0][r], sc[1][r]), fmaxf(sc[2][r], sc[3][r]));
  #pragma unroll
  for (int off = 8; off; off >>= 1)
    #pragma unroll
    for (int r = 0; r < 4; ++r) mr[r] = fmaxf(mr[r], __shfl_xor(mr[r], off, 16));
  #pragma unroll
  for (int r = 0; r < 4; ++r) {
    #pragma unroll
    for (int t = 0; t < 4; ++t) sc[t][r] = __expf(sc[t][r] - mr[r]);
    sr[r] = sc[0][r] + sc[1][r] + sc[2][r] + sc[3][r];
  }
  #pragma unroll
  for (int off = 8; off; off >>= 1)
    #pragma unroll
    for (int r = 0; r < 4; ++r) sr[r] += __shfl_xor(sr[r], off, 16);
  #pragma unroll
  for (int r = 0; r < 4; ++r) sr[r] = 1.f / sr[r];
  // normalized P -> qp_s (q is dead; same-wave write->read, no barrier)
  #pragma unroll
  for (int t = 0; t < 4; ++t)
    #pragma unroll
    for (int r = 0; r < 4; ++r)
      qp_s[(lq * 4 + r) * 72 + t * 16 + lrow] = f2bf(sc[t][r] * sr[r]);

  // ---- PV: all 56 cols; tiles {0,16,32,40}, 4th overlaps (store lrow>=8).
  short8 ap[2];
  #pragma unroll
  for (int kt = 0; kt < 2; ++kt)
    ap[kt] = *(const short8*)&qp_s[lrow * 72 + kt * 32 + lq * 8];
  #pragma unroll
  for (int ct = 0; ct < 4; ++ct) {
    int c0 = (ct < 3) ? ct * 16 : 40;
    int col = c0 + lrow;
    f32x4 ov = {0.f, 0.f, 0.f, 0.f};
    #pragma unroll
    for (int kt = 0; kt < 2; ++kt) {
      short8 bv = *(const short8*)&vT_s[col * 72 + kt * 32 + lq * 8];
      ov = __builtin_amdgcn_mfma_f32_16x16x32_bf16(ap[kt], bv, ov, 0, 0, 0);
    }
    if (ct < 3 || lrow >= 8) {
      #pragma unroll
      for (int r = 0; r < 4; ++r)
        qp_s[(lq * 4 + r) * 72 + col] = f2bf(ov[r]);  // o (head h), same-wave
    }
  }

  // ---- respool compute PRE-barrier (Aw regs + rpF from L2; no LDS deps).
  int nt0 = (wave < 2) ? wave * 4 : 8 + (wave - 2) * 3;
  int ncnt2 = (wave < 2) ? 4 : 3;
  float resv[4][4];
  #pragma unroll
  for (int i = 0; i < 4; ++i) {
    if (i < ncnt2) {  // wave-uniform guard
      int nt = nt0 + i;
      f32x4 racc[4] = {{0.f,0.f,0.f,0.f},{0.f,0.f,0.f,0.f},
                       {0.f,0.f,0.f,0.f},{0.f,0.f,0.f,0.f}};
      short8 rw[4];
      #pragma unroll
      for (int kt = 0; kt < 4; ++kt)
        rw[kt] = *(const short8*)(rpF + (((nt * 4) + kt) * 64 + lane) * 8);
      #pragma unroll
      for (int kt = 0; kt < 4; ++kt)
        #pragma unroll
        for (int mt = 0; mt < 4; ++mt)
          racc[mt] = __builtin_amdgcn_mfma_f32_16x16x32_bf16(Aw[mt][kt], rw[kt], racc[mt], 0, 0, 0);
      float bi = rpb[nt * 16 + lrow];
      #pragma unroll
      for (int mt = 0; mt < 4; ++mt)
        resv[i][mt] = fmaxf(fmaxf(racc[mt][0], racc[mt][1]),
                            fmaxf(racc[mt][2], racc[mt][3])) + bi;
    }
  }
  __syncthreads();  // all heads' o ready; all k/vT regions now DEAD

  // res -> res_s f32[16][228] over dead w_s/k/vT region (same-wave reads later)
  float* res_s = (float*)u_s;
  #pragma unroll
  for (int i = 0; i < 4; ++i) {
    if (i < ncnt2) {
      int nt = nt0 + i;
      #pragma unroll
      for (int mt = 0; mt < 4; ++mt)
        res_s[(mt * 4 + lq) * 228 + nt * 16 + lrow] = resv[i][mt];
    }
  }

  // ---- fused attn_proj: A = o rows 0..15 (K=224 spread over head regions)
  short8 Ao[7];
  #pragma unroll
  for (int kt = 0; kt < 7; ++kt) {
    int c = kt * 32 + lq * 8;               // o channel 0..216
    int h2 = (c >= 168) ? 3 : (c >= 112) ? 2 : (c >= 56) ? 1 : 0;
    Ao[kt] = *(const short8*)&u_s[h2 * 9792 + 8640 + lrow * 72 + (c - h2 * 56)];
  }
  for (int i = 0; i < ncnt2; ++i) {
    int nt = nt0 + i;
    f32x4 acc = {0.f, 0.f, 0.f, 0.f};
    #pragma unroll
    for (int kt = 0; kt < 7; ++kt) {
      short8 bw = *(const short8*)(apF + ((nt * 7 + kt) * 64 + lane) * 8);
      acc = __builtin_amdgcn_mfma_f32_16x16x32_bf16(Ao[kt], bw, acc, 0, 0, 0);
    }
    int col2 = nt * 16 + lrow;
    float bi = apb[col2];
    #pragma unroll
    for (int r = 0; r < 4; ++r) {
      float res = res_s[(lq * 4 + r) * 228 + col2];
      size_t token = ((size_t)(b * 64 + nh * 4 + lq)) * 64 + nw * 4 + r;
      hs2[token * 224 + col2] = res + acc[r] + bi;
    }
  }
}

// ------------- fused LN2 + mlp1 + GELU + mlp2 + residual, 32x32x16 MFMA
// (R16 version: lane=channel epilogues, fused multi-tile GEMM1, res
// prefetch, dual GEMM2 accumulators, vectorized LN2)
template <int NT>
__device__ __forceinline__ void mlp1_tiles(
    int nt0, const short* ln_s, const short* __restrict__ m1F,
    const float* __restrict__ b1, short* hid_s, int nl, int half, int lane) {
  f32x16 acc[NT];
  #pragma unroll
  for (int i = 0; i < NT; ++i)
    #pragma unroll
    for (int r = 0; r < 16; ++r) acc[i][r] = 0.f;
  #pragma unroll
  for (int kt = 0; kt < 14; ++kt) {
    short8 a = *(const short8*)&ln_s[nl * 232 + kt * 16 + half * 8];
    #pragma unroll
    for (int i = 0; i < NT; ++i) {
      short8 bw = *(const short8*)(m1F + ((size_t)((nt0 + i) * 14 + kt) * 64 + lane) * 8);
      acc[i] = __builtin_amdgcn_mfma_f32_32x32x16_bf16(a, bw, acc[i], 0, 0, 0);
    }
  }
  #pragma unroll
  for (int i = 0; i < NT; ++i) {
    int col = (nt0 + i) * 32 + nl;
    float bi = b1[col];
    #pragma unroll
    for (int r = 0; r < 16; ++r) {
      int row = (r & 3) + 8 * (r >> 2) + 4 * half;
      hid_s[row * 904 + col] = f2bf(gelu_fast(acc[i][r] + bi));
    }
  }
}

__global__ __launch_bounds__(512, 4) void mlp_kernel(
    const float* __restrict__ hs2, const float* __restrict__ g2,
    const float* __restrict__ b2, const short* __restrict__ m1F,
    const float* __restrict__ b1, const short* __restrict__ m2F,
    const float* __restrict__ b2b, float* __restrict__ out) {
  __shared__ alignas(16) short ln_s[32 * 232];   // 14,848 B
  __shared__ alignas(16) short hid_s[32 * 904];  // 57,856 B => 72,704 B
  int blk = blockIdx.x;  // 1024 x 32 tokens
  int tid = threadIdx.x;
  size_t base = (size_t)blk * 32 * 224;
  {
    // LN2: lane owns 14 CONTIGUOUS channels; 7x float2 loads, 7x b32 writes
    int row = tid >> 4, l = tid & 15;
    const float* rp = hs2 + base + (size_t)row * 224 + l * 14;
    float v[14];
    float s = 0.f;
    #pragma unroll
    for (int c = 0; c < 7; ++c) {
      float2 t = *(const float2*)(rp + 2 * c);
      v[2 * c] = t.x; v[2 * c + 1] = t.y;
      s += t.x + t.y;
    }
    #pragma unroll
    for (int off = 8; off; off >>= 1) s += __shfl_xor(s, off, 16);
    float mean = s * (1.f / 224.f);
    float s2 = 0.f;
    #pragma unroll
    for (int c = 0; c < 14; ++c) { float d = v[c] - mean; s2 = fmaf(d, d, s2); }
    #pragma unroll
    for (int off = 8; off; off >>= 1) s2 += __shfl_xor(s2, off, 16);
    float rs = rsqrtf(s2 * (1.f / 224.f) + 1e-6f);
    const float* gp = g2 + l * 14;
    const float* bp = b2 + l * 14;
    #pragma unroll
    for (int c = 0; c < 7; ++c) {
      float2 gg = *(const float2*)(gp + 2 * c);
      float2 bb = *(const float2*)(bp + 2 * c);
      unsigned lo = (unsigned short)f2bf((v[2 * c] - mean) * rs * gg.x + bb.x);
      unsigned hi = (unsigned short)f2bf((v[2 * c + 1] - mean) * rs * gg.y + bb.y);
      *(unsigned*)&ln_s[row * 232 + l * 14 + 2 * c] = lo | (hi << 16);
    }
  }
  __syncthreads();
  int wave = tid >> 6, lane = tid & 63;
  int nl = lane & 31, half = lane >> 5;
  if (wave < 4) mlp1_tiles<4>(wave * 4, ln_s, m1F, b1, hid_s, nl, half, lane);
  else          mlp1_tiles<3>(16 + (wave - 4) * 3, ln_s, m1F, b1, hid_s, nl, half, lane);
  __syncthreads();
  if (wave < 7) {
    int nt = wave;
    int col = nt * 32 + nl;
    float res[16];
    #pragma unroll
    for (int r = 0; r < 16; ++r) {
      int row = (r & 3) + 8 * (r >> 2) + 4 * half;
      res[r] = hs2[base + (size_t)row * 224 + col];
    }
    f32x16 ac0 = {0.f,0.f,0.f,0.f,0.f,0.f,0.f,0.f,0.f,0.f,0.f,0.f,0.f,0.f,0.f,0.f};
    f32x16 ac1 = {0.f,0.f,0.f,0.f,0.f,0.f,0.f,0.f,0.f,0.f,0.f,0.f,0.f,0.f,0.f,0.f};
    #pragma unroll 4
    for (int kt = 0; kt < 56; kt += 2) {
      short8 a0 = *(const short8*)&hid_s[nl * 904 + kt * 16 + half * 8];
      short8 a1 = *(const short8*)&hid_s[nl * 904 + (kt + 1) * 16 + half * 8];
      short8 b0 = *(const short8*)(m2F + ((size_t)(nt * 56 + kt) * 64 + lane) * 8);
      short8 b1 = *(const short8*)(m2F + ((size_t)(nt * 56 + kt + 1) * 64 + lane) * 8);
      ac0 = __builtin_amdgcn_mfma_f32_32x32x16_bf16(a0, b0, ac0, 0, 0, 0);
      ac1 = __builtin_amdgcn_mfma_f32_32x32x16_bf16(a1, b1, ac1, 0, 0, 0);
    }
    float bi = b2b[col];
    #pragma unroll
    for (int r = 0; r < 16; ++r) {
      int row = (r & 3) + 8 * (r >> 2) + 4 * half;
      size_t idx = base + (size_t)row * 224 + col;
      out[idx] = res[r] + ac0[r] + ac1[r] + bi;
    }
  }
}

extern "C" void kernel_launch(void* const* d_in, const int* in_sizes, int n_in,
                              void* d_out, int out_size, void* d_ws, size_t ws_size,
                              hipStream_t stream) {
  const float* x    = (const float*)d_in[0];
  const float* ln1g = (const float*)d_in[1];
  const float* ln1b = (const float*)d_in[2];
  const float* qkvw = (const float*)d_in[3];
  const float* qkvb = (const float*)d_in[4];
  const float* apw  = (const float*)d_in[5];
  const float* apb  = (const float*)d_in[6];
  const float* rpw  = (const float*)d_in[7];
  const float* rpb  = (const float*)d_in[8];
  const float* ln2g = (const float*)d_in[9];
  const float* ln2b = (const float*)d_in[10];
  const float* w1   = (const float*)d_in[11];
  const float* b1   = (const float*)d_in[12];
  const float* w2   = (const float*)d_in[13];
  const float* b2   = (const float*)d_in[14];
  float* out = (float*)d_out;

  float* hs2 = (float*)((char*)d_ws + 29360128);
  short* wF  = (short*)((char*)d_ws + 73400320);

  cast_w_kernel<<<1024, 256, 0, stream>>>(qkvw, rpw, apw, w1, w2, wF);
  attn_kernel<<<2048, 256, 0, stream>>>(x, ln1g, ln1b, wF, qkvb, wF + 118784,
                                        apb, wF + 90112, rpb, hs2);
  mlp_kernel<<<1024, 512, 0, stream>>>(hs2, ln2g, ln2b, wF + 168960, b1,
                                       wF + 369664, b2, out);
}